// Round 2
// baseline (289.441 us; speedup 1.0000x reference)
//
#include <hip/hip_runtime.h>
#include <math.h>

#define THREADS 256
#define CHUNKS 512          // stage-1 row chunks -> 4*512 = 2048 blocks (8/CU)

// ---------------- Kernel 1: column partial sums of W (deterministic) -------
__global__ __launch_bounds__(THREADS)
void colsum_partials_kernel(const float* __restrict__ W, float* __restrict__ partials,
                            int O, int N, int rows_per_chunk) {
    int col = (blockIdx.x * THREADS + threadIdx.x) * 4;
    if (col >= N) return;
    int r0 = blockIdx.y * rows_per_chunk;
    int r1 = r0 + rows_per_chunk; if (r1 > O) r1 = O;
    float ax = 0.f, ay = 0.f, az = 0.f, aw = 0.f;
    for (int r = r0; r < r1; ++r) {
        const float4 v = *reinterpret_cast<const float4*>(W + (size_t)r * N + col);
        ax += v.x; ay += v.y; az += v.z; aw += v.w;
    }
    float4* p = reinterpret_cast<float4*>(partials + (size_t)blockIdx.y * N + col);
    *p = make_float4(ax, ay, az, aw);
}

// ------ Kernel 2: reduce partials -> c, plus bias sum in the last block ------
__global__ __launch_bounds__(THREADS)
void reduce_bias_kernel(const float* __restrict__ partials,
                        const float* __restrict__ bias, const float* __restrict__ sub,
                        float* __restrict__ c, float* __restrict__ cb,
                        int N, int chunks, int O) {
    if ((int)blockIdx.x == (int)gridDim.x - 1) {
        // bias/subtract sum
        float s = 0.f;
        for (int i = threadIdx.x; i < O; i += THREADS) s += bias[i] - sub[i];
        #pragma unroll
        for (int off = 32; off > 0; off >>= 1) s += __shfl_down(s, off, 64);
        __shared__ float lds[THREADS / 64];
        const int wave = threadIdx.x >> 6;
        if ((threadIdx.x & 63) == 0) lds[wave] = s;
        __syncthreads();
        if (threadIdx.x == 0) {
            float t = 0.f;
            #pragma unroll
            for (int w = 0; w < THREADS / 64; ++w) t += lds[w];
            *cb = t;
        }
        return;
    }
    const int col = blockIdx.x * THREADS + threadIdx.x;
    if (col >= N) return;
    float a = 0.f;
    for (int k = 0; k < chunks; ++k) a += partials[(size_t)k * N + col];
    c[col] = a;
}

// ---------------- fallback: atomic column sums -------------------------------
__global__ __launch_bounds__(THREADS)
void colsum_atomic_kernel(const float* __restrict__ W, float* __restrict__ c,
                          int O, int N, int rows_per_chunk) {
    int col = (blockIdx.x * THREADS + threadIdx.x) * 4;
    if (col >= N) return;
    int r0 = blockIdx.y * rows_per_chunk;
    int r1 = r0 + rows_per_chunk; if (r1 > O) r1 = O;
    float ax = 0.f, ay = 0.f, az = 0.f, aw = 0.f;
    for (int r = r0; r < r1; ++r) {
        const float4 v = *reinterpret_cast<const float4*>(W + (size_t)r * N + col);
        ax += v.x; ay += v.y; az += v.z; aw += v.w;
    }
    atomicAdd(&c[col + 0], ax);
    atomicAdd(&c[col + 1], ay);
    atomicAdd(&c[col + 2], az);
    atomicAdd(&c[col + 3], aw);
}

__global__ __launch_bounds__(THREADS)
void biassum_kernel(const float* __restrict__ bias, const float* __restrict__ sub,
                    float* __restrict__ out_scalar, int O) {
    float s = 0.f;
    for (int i = threadIdx.x; i < O; i += THREADS) s += bias[i] - sub[i];
    #pragma unroll
    for (int off = 32; off > 0; off >>= 1) s += __shfl_down(s, off, 64);
    __shared__ float lds[THREADS / 64];
    int wave = threadIdx.x >> 6;
    if ((threadIdx.x & 63) == 0) lds[wave] = s;
    __syncthreads();
    if (threadIdx.x == 0) {
        float t = 0.f;
        #pragma unroll
        for (int w = 0; w < THREADS / 64; ++w) t += lds[w];
        *out_scalar = t;
    }
}

// ---------------- Kernel 3: fused row dot -> gelu -> residual add ------------
// One block per row; x row in registers (read once, write once); one barrier.
__device__ __forceinline__ float gelu_tanh(float mm) {
    const float inner = 0.7978845608028654f * (mm + 0.044715f * mm * mm * mm);
    return 0.5f * mm * (1.0f + tanhf(inner));
}

template<int ITERS>
__global__ __launch_bounds__(THREADS)
void row_fused_kernel(const float* __restrict__ x, const float* __restrict__ c,
                      const float* __restrict__ cb, const int* __restrict__ of_ptr,
                      float* __restrict__ out, int N) {
    const size_t base = (size_t)blockIdx.x * N;
    float4 xv[ITERS];
    float partial = 0.f;
    #pragma unroll
    for (int it = 0; it < ITERS; ++it) {
        const int idx = (it * THREADS + threadIdx.x) * 4;
        const float4 xx = *reinterpret_cast<const float4*>(x + base + idx);
        const float4 cc = *reinterpret_cast<const float4*>(c + idx);
        xv[it] = xx;
        partial += xx.x * cc.x + xx.y * cc.y + xx.z * cc.z + xx.w * cc.w;
    }

    #pragma unroll
    for (int off = 32; off > 0; off >>= 1) partial += __shfl_down(partial, off, 64);

    __shared__ float lds[THREADS / 64];
    if ((threadIdx.x & 63) == 0) lds[threadIdx.x >> 6] = partial;
    __syncthreads();

    float rs = *cb;
    #pragma unroll
    for (int w = 0; w < THREADS / 64; ++w) rs += lds[w];
    const float mm = rs / (float)(*of_ptr);
    const float g = gelu_tanh(mm);   // computed by all threads (no 2nd barrier)

    #pragma unroll
    for (int it = 0; it < ITERS; ++it) {
        const int idx = (it * THREADS + threadIdx.x) * 4;
        const float4 xx = xv[it];
        *reinterpret_cast<float4*>(out + base + idx) =
            make_float4(xx.x + g, xx.y + g, xx.z + g, xx.w + g);
    }
}

// generic fallback for unexpected N
__global__ __launch_bounds__(THREADS)
void row_fused_generic_kernel(const float* __restrict__ x, const float* __restrict__ c,
                              const float* __restrict__ cb, const int* __restrict__ of_ptr,
                              float* __restrict__ out, int N) {
    const size_t base = (size_t)blockIdx.x * N;
    float partial = 0.f;
    for (int i = threadIdx.x; i < N; i += THREADS) partial += x[base + i] * c[i];
    #pragma unroll
    for (int off = 32; off > 0; off >>= 1) partial += __shfl_down(partial, off, 64);
    __shared__ float lds[THREADS / 64];
    if ((threadIdx.x & 63) == 0) lds[threadIdx.x >> 6] = partial;
    __syncthreads();
    float rs = *cb;
    #pragma unroll
    for (int w = 0; w < THREADS / 64; ++w) rs += lds[w];
    const float mm = rs / (float)(*of_ptr);
    const float g = gelu_tanh(mm);
    for (int i = threadIdx.x; i < N; i += THREADS) out[base + i] = x[base + i] + g;
}

extern "C" void kernel_launch(void* const* d_in, const int* in_sizes, int n_in,
                              void* d_out, int out_size, void* d_ws, size_t ws_size,
                              hipStream_t stream) {
    const float* x    = (const float*)d_in[0];
    const float* W    = (const float*)d_in[1];
    const float* bias = (const float*)d_in[2];
    const float* sub  = (const float*)d_in[3];
    const int* of_ptr = (const int*)d_in[4];

    const int O = in_sizes[2];                       // 16384
    const int N = (int)((long long)in_sizes[1] / O); // 4096
    const int M = (int)((long long)in_sizes[0] / N); // 16384

    float* ws = (float*)d_ws;
    float* c  = ws;            // N floats
    float* cb = ws + N;        // 1 float (padded to 64)
    float* partials = ws + N + 64;

    const int colblocks = (N + THREADS * 4 - 1) / (THREADS * 4); // 4 for N=4096
    const int rows_per_chunk = (O + CHUNKS - 1) / CHUNKS;        // 32
    const size_t need = ((size_t)N + 64 + (size_t)CHUNKS * N) * sizeof(float);

    if (ws_size >= need) {
        dim3 g1(colblocks, CHUNKS);
        colsum_partials_kernel<<<g1, THREADS, 0, stream>>>(W, partials, O, N, rows_per_chunk);
        const int nb = (N + THREADS - 1) / THREADS + 1;          // 16 col blocks + 1 bias block
        reduce_bias_kernel<<<nb, THREADS, 0, stream>>>(partials, bias, sub, c, cb, N, CHUNKS, O);
    } else {
        hipMemsetAsync(c, 0, (size_t)N * sizeof(float), stream);
        dim3 g1(colblocks, CHUNKS);
        colsum_atomic_kernel<<<g1, THREADS, 0, stream>>>(W, c, O, N, rows_per_chunk);
        biassum_kernel<<<1, THREADS, 0, stream>>>(bias, sub, cb, O);
    }

    const int row_iters = N / (THREADS * 4);
    if (N % (THREADS * 4) == 0 && row_iters == 4) {
        row_fused_kernel<4><<<M, THREADS, 0, stream>>>(x, c, cb, of_ptr, (float*)d_out, N);
    } else if (N % (THREADS * 4) == 0 && row_iters == 8) {
        row_fused_kernel<8><<<M, THREADS, 0, stream>>>(x, c, cb, of_ptr, (float*)d_out, N);
    } else {
        row_fused_generic_kernel<<<M, THREADS, 0, stream>>>(x, c, cb, of_ptr, (float*)d_out, N);
    }
}